// Round 6
// baseline (47.132 us; speedup 1.0000x reference)
//
#include <hip/hip_runtime.h>
#include <math.h>

// Problem constants (compile-time; from reference setup_inputs)
#define BATCH     65536
#define NNBR      8
#define DIM       16
#define HALF_L2W  5.0e-5f            // 0.5 * L2_WEIGHT

// --- streaming kernel geometry ---
#define SBLOCK    256
#define SGRID     2048
#define STH       (SGRID * SBLOCK)         // 524288 threads
// table sizes in float4 units
#define N_E4      8000000                  // 2,000,000 * 16 / 4
#define N_U4      400000                   // 100,000 * 16 / 4
#define N_R4      256                      // 64 * 16 / 4
#define E_ITERS   (N_E4 / STH)             // 15
#define E_TAIL    (N_E4 - E_ITERS * STH)   // 135680

// --- row kernel geometry ---
#define RBLOCK    256
#define RGRID     1024                     // 64 rows/block * 1024 = 65536
#define ROWS_PB   64

// ws layout: ws[0..SGRID-1] = l2 partials, ws[SGRID..SGRID+RGRID-1] = bce partials
#define WS_BCE_OFF SGRID

__device__ __forceinline__ float sq4(float4 v) {
    return v.x * v.x + v.y * v.y + v.z * v.z + v.w * v.w;
}

// ---------------------------------------------------------------------------
// Kernel A: streaming sum-of-squares (also warms L3 with the entity table)
// ---------------------------------------------------------------------------
__global__ void __launch_bounds__(SBLOCK)
stream_l2(const float4* __restrict__ ue4,
          const float4* __restrict__ ee4,
          const float4* __restrict__ re4,
          float* __restrict__ ws) {
    const int tid = blockIdx.x * SBLOCK + threadIdx.x;

    float l2 = 0.0f;
    const float4* p = ee4 + tid;
    #pragma unroll
    for (int k = 0; k < E_ITERS; ++k) l2 += sq4(p[k * STH]);
    if (tid < E_TAIL) l2 += sq4(p[E_ITERS * STH]);
    if (tid < N_U4)   l2 += sq4(ue4[tid]);
    if (tid < N_R4)   l2 += sq4(re4[tid]);

    #pragma unroll
    for (int o = 32; o > 0; o >>= 1) l2 += __shfl_down(l2, o);

    __shared__ float sred[4];
    const int wid = threadIdx.x >> 6;
    if ((threadIdx.x & 63) == 0) sred[wid] = l2;
    __syncthreads();
    if (threadIdx.x == 0)
        ws[blockIdx.x] = sred[0] + sred[1] + sred[2] + sred[3];
}

// ---------------------------------------------------------------------------
// Kernel B: KGCN row work; gathers hit L3 (entity table streamed by kernel A)
// ---------------------------------------------------------------------------
__global__ void __launch_bounds__(RBLOCK)
row_kernel(const float4* __restrict__ ue4,
           const float4* __restrict__ ee4,
           const float4* __restrict__ re4,
           const float*  __restrict__ W,      // [D][D]
           const float4* __restrict__ b4,     // [D/4]
           const float*  __restrict__ labels,
           const int*    __restrict__ uidx,
           const int*    __restrict__ iidx,
           const int4*   __restrict__ adjE4,  // [N_ENTITY][2] int4
           const int4*   __restrict__ adjR4,
           float* __restrict__ ws) {
    // W transposed into LDS: sWT[j*16+i] = W[i][j] (column j contiguous)
    __shared__ float sWT[DIM * DIM];
    __shared__ float4 sbias[DIM / 4];
    sWT[threadIdx.x] = W[(threadIdx.x & 15) * DIM + (threadIdx.x >> 4)];
    if (threadIdx.x < DIM / 4) sbias[threadIdx.x] = b4[threadIdx.x];
    __syncthreads();

    const int lane4 = threadIdx.x & 3;                 // dim-quad index
    const int row   = blockIdx.x * ROWS_PB + (threadIdx.x >> 2);

    const int ui = uidx[row];
    const int it = iidx[row];
    const float4 u4  = ue4[ui * 4 + lane4];
    const float4 sv4 = ee4[it * 4 + lane4];
    const int4 a0 = adjE4[it * 2], a1 = adjE4[it * 2 + 1];
    const int4 r0 = adjR4[it * 2], r1 = adjR4[it * 2 + 1];

    const int ne[NNBR] = {a0.x, a0.y, a0.z, a0.w, a1.x, a1.y, a1.z, a1.w};
    const int nr[NNBR] = {r0.x, r0.y, r0.z, r0.w, r1.x, r1.y, r1.z, r1.w};

    float4 nv[NNBR];
    float sc[NNBR];
    #pragma unroll
    for (int k = 0; k < NNBR; ++k) {
        const float4 rv = re4[nr[k] * 4 + lane4];   // 64 relations -> cache-hot
        nv[k] = ee4[ne[k] * 4 + lane4];             // L3-hit gather
        float s = u4.x * rv.x + u4.y * rv.y + u4.z * rv.z + u4.w * rv.w;
        s += __shfl_xor(s, 1, 4);
        s += __shfl_xor(s, 2, 4);
        sc[k] = s * (1.0f / 16.0f);
    }

    float m = sc[0];
    #pragma unroll
    for (int k = 1; k < NNBR; ++k) m = fmaxf(m, sc[k]);
    float e[NNBR], den = 0.0f;
    #pragma unroll
    for (int k = 0; k < NNBR; ++k) { e[k] = __expf(sc[k] - m); den += e[k]; }
    const float inv = 1.0f / den;

    float4 agg = make_float4(0.f, 0.f, 0.f, 0.f);
    #pragma unroll
    for (int k = 0; k < NNBR; ++k) {
        agg.x += e[k] * nv[k].x; agg.y += e[k] * nv[k].y;
        agg.z += e[k] * nv[k].z; agg.w += e[k] * nv[k].w;
    }

    float4 x4;
    x4.x = sv4.x + agg.x * inv; x4.y = sv4.y + agg.y * inv;
    x4.z = sv4.z + agg.z * inv; x4.w = sv4.w + agg.w * inv;

    // broadcast all 16 x_j across the 4-lane group
    float xall[DIM];
    #pragma unroll
    for (int src = 0; src < 4; ++src) {
        xall[4 * src + 0] = __shfl(x4.x, src, 4);
        xall[4 * src + 1] = __shfl(x4.y, src, 4);
        xall[4 * src + 2] = __shfl(x4.z, src, 4);
        xall[4 * src + 3] = __shfl(x4.w, src, 4);
    }

    const float4* sWT4 = (const float4*)sWT;
    float4 acc = sbias[lane4];
    #pragma unroll
    for (int j = 0; j < DIM; ++j) {
        const float4 wv = sWT4[j * 4 + lane4];
        acc.x += xall[j] * wv.x; acc.y += xall[j] * wv.y;
        acc.z += xall[j] * wv.z; acc.w += xall[j] * wv.w;
    }
    float4 item;
    item.x = tanhf(acc.x); item.y = tanhf(acc.y);
    item.z = tanhf(acc.z); item.w = tanhf(acc.w);

    float lg = u4.x * item.x + u4.y * item.y + u4.z * item.z + u4.w * item.w;
    lg += __shfl_xor(lg, 1, 4);
    lg += __shfl_xor(lg, 2, 4);

    float bce = 0.0f;
    if (lane4 == 0) {
        const float y = labels[row];
        bce = fmaxf(lg, 0.0f) - lg * y + log1pf(__expf(-fabsf(lg)));
    }

    #pragma unroll
    for (int o = 32; o > 0; o >>= 1) bce += __shfl_down(bce, o);

    __shared__ float sred[4];
    const int wid = threadIdx.x >> 6;
    if ((threadIdx.x & 63) == 0) sred[wid] = bce;
    __syncthreads();
    if (threadIdx.x == 0)
        ws[WS_BCE_OFF + blockIdx.x] = sred[0] + sred[1] + sred[2] + sred[3];
}

// ---------------------------------------------------------------------------
// Kernel C: finalize — reduce 2048 l2 partials + 1024 bce partials
// ---------------------------------------------------------------------------
__global__ void __launch_bounds__(256)
finalize_kernel(const float* __restrict__ ws, float* __restrict__ out) {
    float l2 = 0.0f, bce = 0.0f;
    #pragma unroll
    for (int k = 0; k < SGRID / 256; ++k)          // 8 iters
        l2 += ws[threadIdx.x + k * 256];
    #pragma unroll
    for (int k = 0; k < RGRID / 256; ++k)          // 4 iters
        bce += ws[WS_BCE_OFF + threadIdx.x + k * 256];

    #pragma unroll
    for (int o = 32; o > 0; o >>= 1) {
        l2  += __shfl_down(l2, o);
        bce += __shfl_down(bce, o);
    }
    __shared__ float sred[8];
    const int wid = threadIdx.x >> 6;
    if ((threadIdx.x & 63) == 0) { sred[wid] = l2; sred[4 + wid] = bce; }
    __syncthreads();
    if (threadIdx.x == 0) {
        const float l2t  = sred[0] + sred[1] + sred[2] + sred[3];
        const float bcet = sred[4] + sred[5] + sred[6] + sred[7];
        out[0] = bcet * (1.0f / (float)BATCH) + HALF_L2W * l2t;
    }
}

extern "C" void kernel_launch(void* const* d_in, const int* in_sizes, int n_in,
                              void* d_out, int out_size, void* d_ws, size_t ws_size,
                              hipStream_t stream) {
    const float4* ue4    = (const float4*)d_in[0];
    const float4* ee4    = (const float4*)d_in[1];
    const float4* re4    = (const float4*)d_in[2];
    const float*  W      = (const float*)d_in[3];
    const float4* b4     = (const float4*)d_in[4];
    const float*  labels = (const float*)d_in[5];
    const int*    uidx   = (const int*)d_in[6];
    const int*    iidx   = (const int*)d_in[7];
    const int4*   adjE4  = (const int4*)d_in[8];
    const int4*   adjR4  = (const int4*)d_in[9];

    float* ws  = (float*)d_ws;
    float* out = (float*)d_out;

    stream_l2<<<SGRID, SBLOCK, 0, stream>>>(ue4, ee4, re4, ws);

    row_kernel<<<RGRID, RBLOCK, 0, stream>>>(
        ue4, ee4, re4, W, b4, labels, uidx, iidx, adjE4, adjR4, ws);

    finalize_kernel<<<1, 256, 0, stream>>>(ws, out);
}